// Round 10
// baseline (21650.435 us; speedup 1.0000x reference)
//
#include <hip/hip_runtime.h>

// LSTM T=16384, B=32, H=96. 32 blocks x 512 thr (8 waves). R20 = 4586us.
// R22 (k-split to VALU, +3 uniform ds_reads) = 6102us: +222cy/step ~= +24
// LDS instrs x ~10-12cy -> LDS BROADCASTS ARE NOT DEDUPED; the LDS pipe
// charges per instruction. R20 re-model: 24 A-reads + 8 writes + 2 xs ~= 34
// LDS instrs x 12cy ~= 400cy serialized + 120cy first-latency -> the step is
// LDS-PIPE-BOUND at ~672cy, not MFMA-burst-bound. 24 reads is the floor
// (16x16x32 A-fragment = fixed 16B/lane/kt; 32x32 doubles reads; permute
// redistribution uses the same LDS pipe; fewer waves grow the burst).
// R23 (this): garbage-tolerant persistent accumulators. Only reg0 of the
// lane's own tile te is ever read from acc; all other C rows feed nobody.
// So acc persists across steps (stale rows accumulate: <= ~1e5 over 16384
// steps, finite), and per step we set only acc{0,1,2}[0] = gx: 12 C-init
// v_movs -> 3. Read rows get C = gx exactly as R20 -> bit-identical absmax.
// Unchanged from R20 (HW-verified): A = h replicated rows (3x ds_read_b128,
// k-slice 8*h16), B = weights cols (tile t col c -> cell 4t+(c>>2), gate
// c&3), te = min(h16,2) mirror for h16=3, quad DPP tail, e_k prefold,
// scaled-domain c, 513-row slot-shifted history, one barrier/step, bulk fc
// flush per 512-step window.

constexpr int HH   = 96;
constexpr int BB   = 32;
constexpr int TT   = 16384;
constexpr int TH   = 512;   // 8 waves, 2 per SIMD
constexpr int NS   = 512;   // h history window
constexpr int ROWP = 104;   // halves per hist row: 208 B, 16B-aligned

typedef _Float16 f16x8 __attribute__((ext_vector_type(8)));
typedef _Float16 f16x2 __attribute__((ext_vector_type(2)));
typedef float    f32x4 __attribute__((ext_vector_type(4)));

template <int CTRL>
__device__ __forceinline__ float dpp_bcast(float v) {
    int r = __builtin_amdgcn_mov_dpp(__builtin_bit_cast(int, v), CTRL, 0xF, 0xF, true);
    return __builtin_bit_cast(float, r);
}
constexpr int DPP_B1 = 0x55;
constexpr int DPP_B2 = 0xAA;
constexpr int DPP_B3 = 0xFF;

#define LOG2E 1.44269504f

__attribute__((amdgpu_flat_work_group_size(TH, TH)))
__global__ void lstm_kernel(const float* __restrict__ x,
                            const float* __restrict__ w_ih,
                            const float* __restrict__ w_hh,
                            const float* __restrict__ b_ih,
                            const float* __restrict__ b_hh,
                            const float* __restrict__ fc_w,
                            const float* __restrict__ fc_b,
                            float* __restrict__ out) {
    __shared__ __align__(16) _Float16 hist[(NS + 1) * ROWP];  // ~104 KB
    __shared__ __align__(16) float xs[NS];                    // 2 KB x window
    __shared__ float fcw_s[HH];

    const int tid = threadIdx.x;
    const int b   = blockIdx.x;
    const int wv  = tid >> 6;   // wave 0..7, owns cells [12wv, 12wv+12)
    const int l   = tid & 63;
    const int h16 = l >> 4;     // k-group 0..3; tail tile = min(h16,2)
    const int rIn = l & 15;     // col within tile
    const int s   = rIn & 3;    // gate 0..3 (quad lane)
    const int q   = rIn >> 2;   // cell-sub within tile
    const int te  = (h16 == 3) ? 2 : h16;    // tail tile (h16=3 mirrors 2)
    const int j   = 12 * wv + 4 * te + q;    // this lane's cell 0..95

    // B fragments (weights), e_k-prescaled. Tile t col rIn holds W row
    // (gate s, cell 12wv+4t+q); lane's k slice = kt*32 + 8*h16 + e.
    const float ek_s = (s == 2) ? (-2.0f * LOG2E) : (-LOG2E);
    f16x8 Bw[3][3];
#pragma unroll
    for (int t = 0; t < 3; ++t) {
        const float* wrow = w_hh + (s * HH + 12 * wv + 4 * t + q) * HH;
#pragma unroll
        for (int kt = 0; kt < 3; ++kt) {
            const float* wr = wrow + kt * 32 + 8 * h16;
            f16x8 v;
#pragma unroll
            for (int e = 0; e < 8; ++e) v[e] = (_Float16)(wr[e] * ek_s);
            Bw[t][kt] = v;
        }
    }
#pragma unroll
    for (int t = 0; t < 3; ++t)
#pragma unroll
        for (int kt = 0; kt < 3; ++kt) asm volatile("" : "+v"(Bw[t][kt]));

    const float wih2  = w_ih[s * HH + j] * ek_s;
    const float bias2 = (b_ih[s * HH + j] + b_hh[s * HH + j]) * ek_s;
    const float a_mul = (s == 2) ? (-4.0f * LOG2E) : 1.0f;
    const float a_add = (s == 2) ? (2.0f * LOG2E) : 0.0f;
    const bool  te1 = (h16 == 1), te2 = (h16 >= 2);

    const float fcb = fc_b[0];
    float c = 0.0f;   // scaled domain: c' = -2*log2e * c_true

    // Persistent accumulators: rows other than the reader's reg0 are never
    // consumed, so they carry stale sums across steps (bounded, harmless).
    f32x4 acc0 = {0.f, 0.f, 0.f, 0.f};
    f32x4 acc1 = {0.f, 0.f, 0.f, 0.f};
    f32x4 acc2 = {0.f, 0.f, 0.f, 0.f};

    for (int i = tid; i < HH; i += TH) fcw_s[i] = fc_w[i];

    // Bulk fc projection for window [t0, t0+NS): h(t0+i) is in hist row i+1.
    auto flush = [&](int t0) {
        for (int i = tid; i < NS; i += TH) {
            const uint2* hr = (const uint2*)(hist + (i + 1) * ROWP);
            float a = 0.0f;
#pragma unroll
            for (int m = 0; m < 24; ++m) {
                uint2 u = hr[m];
                f16x2 p0 = __builtin_bit_cast(f16x2, u.x);
                f16x2 p1 = __builtin_bit_cast(f16x2, u.y);
                a = fmaf((float)p0.x, fcw_s[4 * m + 0], a);
                a = fmaf((float)p0.y, fcw_s[4 * m + 1], a);
                a = fmaf((float)p1.x, fcw_s[4 * m + 2], a);
                a = fmaf((float)p1.y, fcw_s[4 * m + 3], a);
            }
            out[(t0 + i) * BB + b] = a + fcb + xs[i];
        }
    };

    const _Float16* rd_p;  // h(t-1) k-slice base (8*h16); +4 rows per block
    _Float16*       wr_p;  // h(t) cell slot base

    auto step = [&](float gx, const int ofs) {   // ofs: constant element offset
        const uint4* p = (const uint4*)(rd_p + ofs);
        uint4 u0 = p[0], u1 = p[4], u2 = p[8];   // kt stride: 32 halves = 64B
        const f16x8 a0 = __builtin_bit_cast(f16x8, u0);
        const f16x8 a1 = __builtin_bit_cast(f16x8, u1);
        const f16x8 a2 = __builtin_bit_cast(f16x8, u2);

        // Seed ONLY the element this lane reads back (reg0 = row 4h16, col
        // rIn of each tile); other rows keep stale values (consumed by
        // nobody). 3 v_movs instead of 12.
        acc0[0] = gx;
        acc1[0] = gx;
        acc2[0] = gx;
        // kt-outer: 3 tile-chains interleave; C-forwarding at full rate.
        acc0 = __builtin_amdgcn_mfma_f32_16x16x32_f16(a0, Bw[0][0], acc0, 0, 0, 0);
        acc1 = __builtin_amdgcn_mfma_f32_16x16x32_f16(a0, Bw[1][0], acc1, 0, 0, 0);
        acc2 = __builtin_amdgcn_mfma_f32_16x16x32_f16(a0, Bw[2][0], acc2, 0, 0, 0);
        acc0 = __builtin_amdgcn_mfma_f32_16x16x32_f16(a1, Bw[0][1], acc0, 0, 0, 0);
        acc1 = __builtin_amdgcn_mfma_f32_16x16x32_f16(a1, Bw[1][1], acc1, 0, 0, 0);
        acc2 = __builtin_amdgcn_mfma_f32_16x16x32_f16(a1, Bw[2][1], acc2, 0, 0, 0);
        acc0 = __builtin_amdgcn_mfma_f32_16x16x32_f16(a2, Bw[0][2], acc0, 0, 0, 0);
        acc1 = __builtin_amdgcn_mfma_f32_16x16x32_f16(a2, Bw[1][2], acc1, 0, 0, 0);
        acc2 = __builtin_amdgcn_mfma_f32_16x16x32_f16(a2, Bw[2][2], acc2, 0, 0, 0);

        // Rows are replicas -> reg 0 always; 2-cndmask tile select by te.
        float pre = te1 ? acc1[0] : acc0[0];
        pre       = te2 ? acc2[0] : pre;

        const float act =
            fmaf(__builtin_amdgcn_rcpf(1.0f + __builtin_amdgcn_exp2f(pre)),
                 a_mul, a_add);
        const float fv = dpp_bcast<DPP_B1>(act);
        const float gv = dpp_bcast<DPP_B2>(act);   // already -2k-scaled
        const float ov = dpp_bcast<DPP_B3>(act);
        c = fmaf(fv, c, act * gv);                 // scaled domain
        const float rt = __builtin_amdgcn_rcpf(1.0f + __builtin_amdgcn_exp2f(c));
        const float h  = fmaf(ov + ov, rt, -ov);   // o * tanh(c_true)
        if (s == 0 && h16 < 3) *(wr_p + ofs) = (_Float16)h;
        __syncthreads();
    };

    for (int w = 0; w < TT / NS; ++w) {
        const int t0 = w * NS;
        if (w == 0) {
            if (tid < 48) ((uint32_t*)hist)[tid] = 0u;  // row 0 = h(-1) = 0
        } else {
            flush(t0 - NS);                              // old xs + rows 1..512
            if (tid < 48)                                // row 512 -> row 0
                ((uint32_t*)hist)[tid] = ((const uint32_t*)(hist + NS * ROWP))[tid];
        }
        __syncthreads();
        for (int i = tid; i < NS; i += TH) xs[i] = x[(t0 + i) * BB + b];
        __syncthreads();

        rd_p = hist + 8 * h16;
        wr_p = hist + ROWP + j;
        for (int tt = 0; tt < NS; tt += 4) {
            const float4 xq = *(const float4*)(xs + tt);  // broadcast
            const float gx0 = fmaf(xq.x, wih2, bias2);    // off-chain
            const float gx1 = fmaf(xq.y, wih2, bias2);
            const float gx2 = fmaf(xq.z, wih2, bias2);
            const float gx3 = fmaf(xq.w, wih2, bias2);
            step(gx0, 0 * ROWP);
            step(gx1, 1 * ROWP);
            step(gx2, 2 * ROWP);
            step(gx3, 3 * ROWP);
            rd_p += 4 * ROWP;
            wr_p += 4 * ROWP;
        }
    }
    flush(TT - NS);   // last window (loop ended with a barrier)
}

extern "C" void kernel_launch(void* const* d_in, const int* in_sizes, int n_in,
                              void* d_out, int out_size, void* d_ws, size_t ws_size,
                              hipStream_t stream) {
    const float* x    = (const float*)d_in[0];
    const float* w_ih = (const float*)d_in[1];
    const float* w_hh = (const float*)d_in[2];
    const float* b_ih = (const float*)d_in[3];
    const float* b_hh = (const float*)d_in[4];
    const float* fc_w = (const float*)d_in[5];
    const float* fc_b = (const float*)d_in[6];
    float* out = (float*)d_out;

    lstm_kernel<<<dim3(BB), dim3(TH), 0, stream>>>(x, w_ih, w_hh, b_ih, b_hh,
                                                   fc_w, fc_b, out);
}

// Round 11
// 4579.527 us; speedup vs baseline: 4.7277x; 4.7277x over previous
//
#include <hip/hip_runtime.h>

// LSTM T=16384, B=32, H=96. 32 blocks x 512 thr (8 waves, 2/SIMD).
// R20 = 4586us -- VERIFIED OPTIMUM. This is a pure revert of R23.
// Failed probes bracketing this structure (keep for the record):
//   R18 6-wave: 5142 (burst imbalance {2,2,1,1}); R21 12-wave: 4968 (tail is
//   per-wave redundant, +50% VALU issue); R22 VALU k-split: 6102 (+3 uniform
//   ds_reads/wave -> LDS pipe charges PER INSTRUCTION, broadcasts not
//   deduped); R23 persistent acc w/ element-write: 21650 (element-write into
//   live MFMA C-regs defeats per-step register renaming -> cross-step MFMA
//   serialization + VALU->MFMA hazards; per-step fresh {gx,0,0,0} init is
//   free, scheduled under ds_read shadow); R16/R19 dual sync domains:
//   8286/6623 (wall-clock = per-step LATENCY x T; co-resident recurrences
//   can't shorten each other's chain).
// Step budget @2.4GHz: 672cy = LDS queue ~400 (34 LDS instrs x ~12cy; 24
// A-reads forced by fragment replication across waves) || MFMA pipe 350
// (18/SIMD x 19.4cy, W-independent when W%4==0) || serial chain ~300
// (barrier + ds_read latency + MFMA lat + exp2/rcp tail + write).
// Structure (HW-verified): A = h(t-1) replicated rows (3x ds_read_b128,
// k-slice 8*h16), B = weights cols (tile t col c -> cell 12wv+4t+(c>>2),
// gate c&3), gx seeded in C reg0 ({gx,0,0,0} fresh per step), te=min(h16,2)
// mirror for h16=3, quad DPP tail, e_k prefold, scaled-domain c' = -2k*c,
// 513-row slot-shifted history, one barrier/step, bulk fc flush per window.

constexpr int HH   = 96;
constexpr int BB   = 32;
constexpr int TT   = 16384;
constexpr int TH   = 512;   // 8 waves, 2 per SIMD
constexpr int NS   = 512;   // h history window
constexpr int ROWP = 104;   // halves per hist row: 208 B, 16B-aligned

typedef _Float16 f16x8 __attribute__((ext_vector_type(8)));
typedef _Float16 f16x2 __attribute__((ext_vector_type(2)));
typedef float    f32x4 __attribute__((ext_vector_type(4)));

template <int CTRL>
__device__ __forceinline__ float dpp_bcast(float v) {
    int r = __builtin_amdgcn_mov_dpp(__builtin_bit_cast(int, v), CTRL, 0xF, 0xF, true);
    return __builtin_bit_cast(float, r);
}
constexpr int DPP_B1 = 0x55;
constexpr int DPP_B2 = 0xAA;
constexpr int DPP_B3 = 0xFF;

#define LOG2E 1.44269504f

__attribute__((amdgpu_flat_work_group_size(TH, TH)))
__global__ void lstm_kernel(const float* __restrict__ x,
                            const float* __restrict__ w_ih,
                            const float* __restrict__ w_hh,
                            const float* __restrict__ b_ih,
                            const float* __restrict__ b_hh,
                            const float* __restrict__ fc_w,
                            const float* __restrict__ fc_b,
                            float* __restrict__ out) {
    __shared__ __align__(16) _Float16 hist[(NS + 1) * ROWP];  // ~104 KB
    __shared__ __align__(16) float xs[NS];                    // 2 KB x window
    __shared__ float fcw_s[HH];

    const int tid = threadIdx.x;
    const int b   = blockIdx.x;
    const int wv  = tid >> 6;   // wave 0..7, owns cells [12wv, 12wv+12)
    const int l   = tid & 63;
    const int h16 = l >> 4;     // k-group 0..3; tail tile = min(h16,2)
    const int rIn = l & 15;     // col within tile
    const int s   = rIn & 3;    // gate 0..3 (quad lane)
    const int q   = rIn >> 2;   // cell-sub within tile
    const int te  = (h16 == 3) ? 2 : h16;    // tail tile (h16=3 mirrors 2)
    const int j   = 12 * wv + 4 * te + q;    // this lane's cell 0..95

    // B fragments (weights), e_k-prescaled. Tile t col rIn holds W row
    // (gate s, cell 12wv+4t+q); lane's k slice = kt*32 + 8*h16 + e.
    const float ek_s = (s == 2) ? (-2.0f * LOG2E) : (-LOG2E);
    f16x8 Bw[3][3];
#pragma unroll
    for (int t = 0; t < 3; ++t) {
        const float* wrow = w_hh + (s * HH + 12 * wv + 4 * t + q) * HH;
#pragma unroll
        for (int kt = 0; kt < 3; ++kt) {
            const float* wr = wrow + kt * 32 + 8 * h16;
            f16x8 v;
#pragma unroll
            for (int e = 0; e < 8; ++e) v[e] = (_Float16)(wr[e] * ek_s);
            Bw[t][kt] = v;
        }
    }
#pragma unroll
    for (int t = 0; t < 3; ++t)
#pragma unroll
        for (int kt = 0; kt < 3; ++kt) asm volatile("" : "+v"(Bw[t][kt]));

    const float wih2  = w_ih[s * HH + j] * ek_s;
    const float bias2 = (b_ih[s * HH + j] + b_hh[s * HH + j]) * ek_s;
    const float a_mul = (s == 2) ? (-4.0f * LOG2E) : 1.0f;
    const float a_add = (s == 2) ? (2.0f * LOG2E) : 0.0f;
    const bool  te1 = (h16 == 1), te2 = (h16 >= 2);

    const float fcb = fc_b[0];
    float c = 0.0f;   // scaled domain: c' = -2*log2e * c_true

    for (int i = tid; i < HH; i += TH) fcw_s[i] = fc_w[i];

    // Bulk fc projection for window [t0, t0+NS): h(t0+i) is in hist row i+1.
    auto flush = [&](int t0) {
        for (int i = tid; i < NS; i += TH) {
            const uint2* hr = (const uint2*)(hist + (i + 1) * ROWP);
            float a = 0.0f;
#pragma unroll
            for (int m = 0; m < 24; ++m) {
                uint2 u = hr[m];
                f16x2 p0 = __builtin_bit_cast(f16x2, u.x);
                f16x2 p1 = __builtin_bit_cast(f16x2, u.y);
                a = fmaf((float)p0.x, fcw_s[4 * m + 0], a);
                a = fmaf((float)p0.y, fcw_s[4 * m + 1], a);
                a = fmaf((float)p1.x, fcw_s[4 * m + 2], a);
                a = fmaf((float)p1.y, fcw_s[4 * m + 3], a);
            }
            out[(t0 + i) * BB + b] = a + fcb + xs[i];
        }
    };

    const _Float16* rd_p;  // h(t-1) k-slice base (8*h16); +4 rows per block
    _Float16*       wr_p;  // h(t) cell slot base

    auto step = [&](float gx, const int ofs) {   // ofs: constant element offset
        const uint4* p = (const uint4*)(rd_p + ofs);
        uint4 u0 = p[0], u1 = p[4], u2 = p[8];   // kt stride: 32 halves = 64B
        const f16x8 a0 = __builtin_bit_cast(f16x8, u0);
        const f16x8 a1 = __builtin_bit_cast(f16x8, u1);
        const f16x8 a2 = __builtin_bit_cast(f16x8, u2);

        // C-init carries gx: lane (h16,rIn) seeds elem (row 4h16, col rIn)
        // of every tile and reads back exactly its own seed from tile te.
        // Fresh per-step init (movs hide under ds_read latency; R23 showed
        // element-writes into persistent acc regs serialize the loop).
        const f32x4 cz = {gx, 0.f, 0.f, 0.f};
        f32x4 acc[3] = {cz, cz, cz};
        // kt-outer: 3 tile-chains interleave; C-forwarding runs at full rate.
#pragma unroll
        for (int t = 0; t < 3; ++t)
            acc[t] = __builtin_amdgcn_mfma_f32_16x16x32_f16(a0, Bw[t][0], acc[t], 0, 0, 0);
#pragma unroll
        for (int t = 0; t < 3; ++t)
            acc[t] = __builtin_amdgcn_mfma_f32_16x16x32_f16(a1, Bw[t][1], acc[t], 0, 0, 0);
#pragma unroll
        for (int t = 0; t < 3; ++t)
            acc[t] = __builtin_amdgcn_mfma_f32_16x16x32_f16(a2, Bw[t][2], acc[t], 0, 0, 0);

        // Rows are replicas -> reg 0 always; 2-cndmask tile select by te.
        float pre = te1 ? acc[1][0] : acc[0][0];
        pre       = te2 ? acc[2][0] : pre;

        const float act =
            fmaf(__builtin_amdgcn_rcpf(1.0f + __builtin_amdgcn_exp2f(pre)),
                 a_mul, a_add);
        const float fv = dpp_bcast<DPP_B1>(act);
        const float gv = dpp_bcast<DPP_B2>(act);   // already -2k-scaled
        const float ov = dpp_bcast<DPP_B3>(act);
        c = fmaf(fv, c, act * gv);                 // scaled domain
        const float rt = __builtin_amdgcn_rcpf(1.0f + __builtin_amdgcn_exp2f(c));
        const float h  = fmaf(ov + ov, rt, -ov);   // o * tanh(c_true)
        if (s == 0 && h16 < 3) *(wr_p + ofs) = (_Float16)h;
        __syncthreads();
    };

    for (int w = 0; w < TT / NS; ++w) {
        const int t0 = w * NS;
        if (w == 0) {
            if (tid < 48) ((uint32_t*)hist)[tid] = 0u;  // row 0 = h(-1) = 0
        } else {
            flush(t0 - NS);                              // old xs + rows 1..512
            if (tid < 48)                                // row 512 -> row 0
                ((uint32_t*)hist)[tid] = ((const uint32_t*)(hist + NS * ROWP))[tid];
        }
        __syncthreads();
        for (int i = tid; i < NS; i += TH) xs[i] = x[(t0 + i) * BB + b];
        __syncthreads();

        rd_p = hist + 8 * h16;
        wr_p = hist + ROWP + j;
        for (int tt = 0; tt < NS; tt += 4) {
            const float4 xq = *(const float4*)(xs + tt);  // broadcast
            const float gx0 = fmaf(xq.x, wih2, bias2);    // off-chain
            const float gx1 = fmaf(xq.y, wih2, bias2);
            const float gx2 = fmaf(xq.z, wih2, bias2);
            const float gx3 = fmaf(xq.w, wih2, bias2);
            step(gx0, 0 * ROWP);
            step(gx1, 1 * ROWP);
            step(gx2, 2 * ROWP);
            step(gx3, 3 * ROWP);
            rd_p += 4 * ROWP;
            wr_p += 4 * ROWP;
        }
    }
    flush(TT - NS);   // last window (loop ended with a barrier)
}

extern "C" void kernel_launch(void* const* d_in, const int* in_sizes, int n_in,
                              void* d_out, int out_size, void* d_ws, size_t ws_size,
                              hipStream_t stream) {
    const float* x    = (const float*)d_in[0];
    const float* w_ih = (const float*)d_in[1];
    const float* w_hh = (const float*)d_in[2];
    const float* b_ih = (const float*)d_in[3];
    const float* b_hh = (const float*)d_in[4];
    const float* fc_w = (const float*)d_in[5];
    const float* fc_b = (const float*)d_in[6];
    float* out = (float*)d_out;

    lstm_kernel<<<dim3(BB), dim3(TH), 0, stream>>>(x, w_ih, w_hh, b_ih, b_hh,
                                                   fc_w, fc_b, out);
}